// Round 5
// baseline (276.430 us; speedup 1.0000x reference)
//
#include <hip/hip_runtime.h>
#include <hip/hip_bf16.h>

// Problem geometry (fixed by the reference):
//   x: (B=16, C=64, S=512, S=512) fp32
//   out: (16, 64, 256, 256) fp32
//   out[b,c,ho,wo] = w[c] * mean(x[b,c,2ho:2ho+2,2wo:2wo+2]) + bias[c]

#define B_ 16
#define C_ 64
#define S_ 512
#define HO (S_ / 2)   // 256
#define WO (S_ / 2)   // 256

// One wave iteration = 4 consecutive output rows (one "quad" unit):
//   reads input rows [8q, 8q+8) of a channel plane — contiguous 16 KiB/wave
//   writes output rows [4q, 4q+4)                  — contiguous 4 KiB/wave
// Lane i handles input cols [8i, 8i+8) (two float4 per input row).
#define QUADS_PER_CH  (HO / 4)                    // 64
#define QUADS_TOTAL   (B_ * C_ * QUADS_PER_CH)    // 65536

typedef float f32x4 __attribute__((ext_vector_type(4)));

__global__ __launch_bounds__(256) void avgpool_affine_kernel(
    const float* __restrict__ x,
    const float* __restrict__ weight,
    const float* __restrict__ bias,
    float* __restrict__ out)
{
    const int lane     = threadIdx.x & 63;
    const int wave     = (blockIdx.x * blockDim.x + threadIdx.x) >> 6;
    const int numWaves = (gridDim.x * blockDim.x) >> 6;

    for (int u = wave; u < QUADS_TOTAL; u += numWaves)
    {
        const int q  = u & (QUADS_PER_CH - 1);    // 0..63
        const int bc = u >> 6;                    // b*C + c
        const int c  = bc & (C_ - 1);

        const long long ibase = (long long)bc * (S_ * S_)
                              + (long long)(8 * q) * S_ + 8 * lane;

        // 16 independent loads: input rows 8q..8q+7, two float4 per row.
        f32x4 r[8][2];
#pragma unroll
        for (int j = 0; j < 8; ++j) {
            r[j][0] = __builtin_nontemporal_load(
                reinterpret_cast<const f32x4*>(x + ibase + (long long)j * S_));
            r[j][1] = __builtin_nontemporal_load(
                reinterpret_cast<const f32x4*>(x + ibase + (long long)j * S_ + 4));
        }

        const float w  = weight[c];
        const float bs = bias[c];

        const long long obase = (long long)bc * (HO * WO)
                              + (long long)(4 * q) * WO + 4 * lane;

#pragma unroll
        for (int j = 0; j < 4; ++j) {
            const f32x4 t0 = r[2 * j][0], t1 = r[2 * j][1];
            const f32x4 u0 = r[2 * j + 1][0], u1 = r[2 * j + 1][1];
            f32x4 o;
            o.x = __builtin_fmaf(w, 0.25f * (t0.x + t0.y + u0.x + u0.y), bs);
            o.y = __builtin_fmaf(w, 0.25f * (t0.z + t0.w + u0.z + u0.w), bs);
            o.z = __builtin_fmaf(w, 0.25f * (t1.x + t1.y + u1.x + u1.y), bs);
            o.w = __builtin_fmaf(w, 0.25f * (t1.z + t1.w + u1.z + u1.w), bs);
            __builtin_nontemporal_store(
                o, reinterpret_cast<f32x4*>(out + obase + (long long)j * WO));
        }
    }
}

extern "C" void kernel_launch(void* const* d_in, const int* in_sizes, int n_in,
                              void* d_out, int out_size, void* d_ws, size_t ws_size,
                              hipStream_t stream)
{
    const float* x      = (const float*)d_in[0];
    const float* weight = (const float*)d_in[1];
    const float* bias   = (const float*)d_in[2];
    float* out          = (float*)d_out;

    const int block = 256;   // 4 waves/block
    const int grid  = 2048;  // 8192 waves; 8 quad units per wave, no tail
    avgpool_affine_kernel<<<grid, block, 0, stream>>>(x, weight, bias, out);
}